// Round 4
// baseline (1032.374 us; speedup 1.0000x reference)
//
#include <hip/hip_runtime.h>

// VQ quantizer, fp32: z [131072,64], e [2048,64].
// d_out (flat float32): z_q [131072*64] | argmin indices [131072] (floats) | loss [1].
//
// Stage 1: brute-force fp32 scan, 1 z-row per thread; metric m = e_sq - 2*z.e
// (z_sq is a per-row constant, order-preserving). Top-2 tracked; rows with
// min2-min1 < 1e-3 (~50x the fp32 error bound) are queued for stage 2.
// Stage 2: exact f64 re-solve (full 2048-code rescan) for queued rows only.
// T=0 => z_out = z + (z_q - z) ~= z_q; we write z_q = e[best] directly.

#define N_ROWS 131072
#define ZD 64
#define KCODES 2048
#define FLAG_CAP 8192
#define GAP_EPS 1e-3f

// ws layout (4-byte units):
// [0] loss accumulator (float)
// [1] flagged-row count (unsigned int)
// [8 .. 8+2048)      e_sq (float)
// [4096 .. 4096+FLAG_CAP) flagged row ids (unsigned int)

__global__ void prep_kernel(const float* __restrict__ e, float* __restrict__ ws) {
    int t = threadIdx.x;                       // single block of 256
    if (t == 0) { ws[0] = 0.0f; ((unsigned int*)ws)[1] = 0u; }
    for (int c = t; c < KCODES; c += 256) {
        const float* p = e + c * ZD;
        float s = 0.0f;
        for (int k = 0; k < ZD; k++) s = fmaf(p[k], p[k], s);
        ws[8 + c] = s;
    }
}

__global__ __launch_bounds__(256) void vq_scan(const float* __restrict__ z,
                                               const float* __restrict__ e,
                                               float* __restrict__ ws,
                                               float* __restrict__ out) {
    int row = blockIdx.x * 256 + threadIdx.x;
    const float* esq = ws + 8;

    // load z row (float4) and compute z_sq
    float4 zv[16];
    const float4* zp4 = (const float4*)(const void*)(z + (size_t)row * ZD);
    for (int j = 0; j < 16; j++) zv[j] = zp4[j];
    const float* zr = (const float*)zv;
    float zsq = 0.0f;
    for (int k = 0; k < ZD; k++) zsq = fmaf(zr[k], zr[k], zsq);

    float min1 = 3.0e38f, min2 = 3.0e38f;
    int best = 0;
    for (int c = 0; c < KCODES; c++) {
        const float* ep = e + c * ZD;          // wave-uniform address
        float dot = 0.0f;
#pragma unroll
        for (int k = 0; k < ZD; k++) dot = fmaf(zr[k], ep[k], dot);
        float m = fmaf(-2.0f, dot, esq[c]);
        bool lt = m < min1;                    // strict: first index wins ties
        min2 = lt ? min1 : fminf(min2, m);
        best = lt ? c : best;
        min1 = lt ? m : min1;
    }

    // queue near-tie rows for exact f64 re-solve
    if (min2 - min1 < GAP_EPS) {
        unsigned int i = atomicAdd(&((unsigned int*)ws)[1], 1u);
        if (i < FLAG_CAP) ((unsigned int*)ws)[4096 + i] = row;
    }

    // z_q = e[best]; indices as float
    const float4* eb = (const float4*)(const void*)(e + (size_t)best * ZD);
    float4* ob = (float4*)(void*)(out + (size_t)row * ZD);
    for (int j = 0; j < 16; j++) ob[j] = eb[j];
    out[(size_t)N_ROWS * ZD + row] = (float)best;

    // loss term = d2 = z_sq + m ; reduce per block, one atomic per block
    float l = zsq + min1;
    for (int off = 1; off < 64; off <<= 1) l += __shfl_xor(l, off, 64);
    __shared__ float sm[4];
    int lane = threadIdx.x & 63, w = threadIdx.x >> 6;
    if (lane == 0) sm[w] = l;
    __syncthreads();
    if (threadIdx.x == 0) atomicAdd(ws, sm[0] + sm[1] + sm[2] + sm[3]);
}

__global__ void vq_fixup(const float* __restrict__ z, const float* __restrict__ e,
                         float* __restrict__ ws, float* __restrict__ out) {
    unsigned int cnt = ((unsigned int*)ws)[1];
    if (cnt > FLAG_CAP) cnt = FLAG_CAP;
    int lane = threadIdx.x;                    // 64 threads = 1 wave per block
    for (unsigned int u = blockIdx.x; u < cnt; u += gridDim.x) {
        int row = (int)((unsigned int*)ws)[4096 + u];
        const float* zp = z + (size_t)row * ZD;
        double dbest = 1.0e300;
        int ibest = 0;
        for (int c = lane; c < KCODES; c += 64) {
            const float* ep = e + (size_t)c * ZD;
            double d = 0.0;
            for (int k = 0; k < ZD; k++) {
                double t = (double)zp[k] - (double)ep[k];
                d = fma(t, t, d);
            }
            if (d < dbest) { dbest = d; ibest = c; }   // ascending c: first wins
        }
        for (int off = 1; off < 64; off <<= 1) {
            double od = __shfl_xor(dbest, off, 64);
            int    oi = __shfl_xor(ibest, off, 64);
            if (od < dbest || (od == dbest && oi < ibest)) { dbest = od; ibest = oi; }
        }
        if (lane < 16)
            ((float4*)(void*)(out + (size_t)row * ZD))[lane] =
                ((const float4*)(const void*)(e + (size_t)ibest * ZD))[lane];
        if (lane == 0) out[(size_t)N_ROWS * ZD + row] = (float)ibest;
        // loss correction from a flipped near-tie is < 1e-3 per row over
        // ~dozens of rows / 8.4M terms => < 1e-8 absolute: ignored.
    }
}

__global__ void finalize_kernel(const float* __restrict__ ws,
                                float* __restrict__ out) {
    out[(size_t)N_ROWS * ZD + N_ROWS] = ws[0] * (1.0f / 8388608.0f);
}

extern "C" void kernel_launch(void* const* d_in, const int* in_sizes, int n_in,
                              void* d_out, int out_size, void* d_ws, size_t ws_size,
                              hipStream_t stream) {
    const float* z = (const float*)d_in[0];
    const float* e = (const float*)d_in[1];
    float* out = (float*)d_out;
    float* ws  = (float*)d_ws;

    prep_kernel<<<dim3(1), dim3(256), 0, stream>>>(e, ws);
    vq_scan<<<dim3(512), dim3(256), 0, stream>>>(z, e, ws, out);
    vq_fixup<<<dim3(64), dim3(64), 0, stream>>>(z, e, ws, out);
    finalize_kernel<<<dim3(1), dim3(1), 0, stream>>>(ws, out);
}

// Round 5
// 411.345 us; speedup vs baseline: 2.5098x; 2.5098x over previous
//
#include <hip/hip_runtime.h>

// VQ quantizer, fp32 in/out: z [131072,64], e [2048,64].
// d_out (flat f32): z_q [131072*64] | indices [131072] (floats) | loss [1].
//
// bf16x3 split-precision MFMA scan: dot(z,e) ~= zh.eh + zh.el + zl.eh (fp32 acc),
// metric = e_sq - 2*dot. Top-2 tracked; rows with gap < 0.08 (worst-case split
// error ~0.035) re-solved exactly in f64. Loss recomputed exactly in fp32 from
// gathered e[best]. T=0 => z_out = z_q = e[best].

#define N_ROWS 131072
#define ZD 64
#define KCODES 2048
#define FLAG_CAP 65536
#define GAP_EPS 0.08f

using bf16x8  = __attribute__((ext_vector_type(8))) short;
using floatx4 = __attribute__((ext_vector_type(4))) float;

__device__ inline float bf2f(unsigned short u) {
    union { unsigned int i; float f; } c; c.i = ((unsigned int)u) << 16; return c.f;
}
__device__ inline unsigned short f2bf(float x) {
    union { float f; unsigned int i; } c; c.f = x;
    unsigned int b = c.i + 0x7FFFu + ((c.i >> 16) & 1u);
    return (unsigned short)(b >> 16);
}

// ws layout (bytes): [0] loss f32 | [4] flag count u32 | [32..8224) e_sq f32[2048]
// [16384..278528) e_hi u16[131072] | [278528..540672) e_lo | [540672..) flags u32

__global__ void prep_kernel(const float* __restrict__ e, float* __restrict__ ws) {
    int c = blockIdx.x * 256 + threadIdx.x;       // 8 blocks -> 2048 codes
    if (c == 0) { ws[0] = 0.0f; ((unsigned int*)ws)[1] = 0u; }
    unsigned short* ehi = (unsigned short*)((char*)ws + 16384);
    unsigned short* elo = ehi + KCODES * ZD;
    const float* p = e + (size_t)c * ZD;
    float s = 0.0f;
    for (int k = 0; k < ZD; k++) {
        float x = p[k];
        s = fmaf(x, x, s);
        unsigned short h = f2bf(x);
        ehi[(size_t)c * ZD + k] = h;
        elo[(size_t)c * ZD + k] = f2bf(x - bf2f(h));
    }
    ws[8 + c] = s;
}

__global__ __launch_bounds__(256) void vq_mfma(
        const float* __restrict__ z, const float* __restrict__ e,
        float* __restrict__ ws, float* __restrict__ out) {
    const float* esq = ws + 8;
    const unsigned short* ehi = (const unsigned short*)((const char*)ws + 16384);
    const unsigned short* elo = ehi + KCODES * ZD;
    unsigned int* cntp  = (unsigned int*)ws + 1;
    unsigned int* flags = (unsigned int*)((char*)ws + 540672);

    int lane = threadIdx.x & 63;
    int w    = threadIdx.x >> 6;
    int wid  = blockIdx.x * 4 + w;                // 0..2047
    int row0 = wid * 64;
    int lrow = lane & 15;
    int lq   = lane >> 4;

    // Build resident A fragments (hi+lo) from fp32 z. A[m=lane&15][k=lq*8+j].
    bf16x8 Ah[4][2], Al[4][2];
#pragma unroll
    for (int rf = 0; rf < 4; rf++)
#pragma unroll
        for (int kc = 0; kc < 2; kc++) {
            const float* zp = z + (size_t)(row0 + rf * 16 + lrow) * ZD + kc * 32 + lq * 8;
            float xv[8];
            *(float4*)(void*)&xv[0] = *(const float4*)(const void*)zp;
            *(float4*)(void*)&xv[4] = *(const float4*)(const void*)(zp + 4);
            bf16x8 h, l;
#pragma unroll
            for (int j = 0; j < 8; j++) {
                unsigned short hb = f2bf(xv[j]);
                h[j] = (short)hb;
                l[j] = (short)f2bf(xv[j] - bf2f(hb));
            }
            Ah[rf][kc] = h; Al[rf][kc] = l;
        }

    floatx4 mval[4], mv2[4], midx[4];
#pragma unroll
    for (int rf = 0; rf < 4; rf++)
#pragma unroll
        for (int r = 0; r < 4; r++) {
            mval[rf][r] = 3.0e38f; mv2[rf][r] = 3.0e38f; midx[rf][r] = 0.0f;
        }

    const unsigned short* bh = ehi + lrow * ZD + lq * 8;
    const unsigned short* bl = elo + lrow * ZD + lq * 8;
    bf16x8 h0 = *(const bf16x8*)(const void*)(bh);
    bf16x8 h1 = *(const bf16x8*)(const void*)(bh + 32);
    bf16x8 l0 = *(const bf16x8*)(const void*)(bl);
    bf16x8 l1 = *(const bf16x8*)(const void*)(bl + 32);
    float  es = esq[lrow];

    for (int ct = 0; ct < 128; ct++) {
        int nn = ((ct + 1) & 127) * 16;           // next tile (wraps; harmless)
        int noff = nn * ZD;
        bf16x8 nh0 = *(const bf16x8*)(const void*)(bh + noff);
        bf16x8 nh1 = *(const bf16x8*)(const void*)(bh + noff + 32);
        bf16x8 nl0 = *(const bf16x8*)(const void*)(bl + noff);
        bf16x8 nl1 = *(const bf16x8*)(const void*)(bl + noff + 32);
        float  nes = esq[nn + lrow];

        float fcol = (float)(ct * 16 + lrow);
#pragma unroll
        for (int rf = 0; rf < 4; rf++) {
            floatx4 acc = {0.0f, 0.0f, 0.0f, 0.0f};
            acc = __builtin_amdgcn_mfma_f32_16x16x32_bf16(Ah[rf][0], h0, acc, 0, 0, 0);
            acc = __builtin_amdgcn_mfma_f32_16x16x32_bf16(Ah[rf][1], h1, acc, 0, 0, 0);
            acc = __builtin_amdgcn_mfma_f32_16x16x32_bf16(Ah[rf][0], l0, acc, 0, 0, 0);
            acc = __builtin_amdgcn_mfma_f32_16x16x32_bf16(Ah[rf][1], l1, acc, 0, 0, 0);
            acc = __builtin_amdgcn_mfma_f32_16x16x32_bf16(Al[rf][0], h0, acc, 0, 0, 0);
            acc = __builtin_amdgcn_mfma_f32_16x16x32_bf16(Al[rf][1], h1, acc, 0, 0, 0);
#pragma unroll
            for (int r = 0; r < 4; r++) {
                float m  = fmaf(acc[r], -2.0f, es);
                bool  lt = m < mval[rf][r];
                float old1 = mval[rf][r];
                mv2[rf][r]  = lt ? old1 : fminf(mv2[rf][r], m);
                midx[rf][r] = lt ? fcol : midx[rf][r];
                mval[rf][r] = lt ? m    : mval[rf][r];
            }
        }
        h0 = nh0; h1 = nh1; l0 = nl0; l1 = nl1; es = nes;
    }

    float lacc = 0.0f;
#pragma unroll
    for (int rf = 0; rf < 4; rf++)
#pragma unroll
        for (int r = 0; r < 4; r++) {
            float v = mval[rf][r], v2 = mv2[rf][r], fi = midx[rf][r];
            // top-2 merge across the 16 lanes of this row (first-index ties)
            for (int off = 1; off < 16; off <<= 1) {
                float ov  = __shfl_xor(v,  off, 64);
                float ofi = __shfl_xor(fi, off, 64);
                float ov2 = __shfl_xor(v2, off, 64);
                bool take = (ov < v) || ((ov == v) && (ofi < fi));
                float loser = take ? v : ov;
                v2 = fminf(fminf(v2, ov2), loser);
                v  = take ? ov  : v;
                fi = take ? ofi : fi;
            }
            int row = row0 + rf * 16 + lq * 4 + r;
            int idx = (int)fi;
            float4 ev = ((const float4*)(const void*)(e + (size_t)idx * ZD))[lrow];
            float4 zv = ((const float4*)(const void*)(z + (size_t)row * ZD))[lrow];
            ((float4*)(void*)(out + (size_t)row * ZD))[lrow] = ev;
            float dx = ev.x - zv.x, dy = ev.y - zv.y;
            float dz = ev.z - zv.z, dw = ev.w - zv.w;
            lacc = fmaf(dx, dx, lacc); lacc = fmaf(dy, dy, lacc);
            lacc = fmaf(dz, dz, lacc); lacc = fmaf(dw, dw, lacc);
            if (lrow == 0) {
                out[(size_t)N_ROWS * ZD + row] = fi;
                if (v2 - v < GAP_EPS) {
                    unsigned int i = atomicAdd(cntp, 1u);
                    if (i < FLAG_CAP) flags[i] = (unsigned int)row;
                }
            }
        }

    for (int off = 1; off < 64; off <<= 1) lacc += __shfl_xor(lacc, off, 64);
    __shared__ float sm[4];
    if (lane == 0) sm[w] = lacc;
    __syncthreads();
    if (threadIdx.x == 0) atomicAdd(ws, sm[0] + sm[1] + sm[2] + sm[3]);
}

__global__ void vq_fixup(const float* __restrict__ z, const float* __restrict__ e,
                         float* __restrict__ ws, float* __restrict__ out) {
    unsigned int cnt = ((unsigned int*)ws)[1];
    if (cnt > FLAG_CAP) cnt = FLAG_CAP;
    const unsigned int* flags = (const unsigned int*)((const char*)ws + 540672);
    int lane = threadIdx.x;                      // 64 threads = 1 wave per block
    for (unsigned int u = blockIdx.x; u < cnt; u += gridDim.x) {
        int row = (int)flags[u];
        const float* zp = z + (size_t)row * ZD;
        double dbest = 1.0e300;
        int ibest = 0;
        for (int c = lane; c < KCODES; c += 64) {
            const float* ep = e + (size_t)c * ZD;
            double d = 0.0;
            for (int k = 0; k < ZD; k++) {
                double t = (double)zp[k] - (double)ep[k];
                d = fma(t, t, d);
            }
            if (d < dbest) { dbest = d; ibest = c; }   // ascending c: first wins
        }
        for (int off = 1; off < 64; off <<= 1) {
            double od = __shfl_xor(dbest, off, 64);
            int    oi = __shfl_xor(ibest, off, 64);
            if (od < dbest || (od == dbest && oi < ibest)) { dbest = od; ibest = oi; }
        }
        if (lane < 16)
            ((float4*)(void*)(out + (size_t)row * ZD))[lane] =
                ((const float4*)(const void*)(e + (size_t)ibest * ZD))[lane];
        if (lane == 0) out[(size_t)N_ROWS * ZD + row] = (float)ibest;
        // loss correction from a flipped near-tie: < 0.08 * ~2e3 rows / 8.4M
        // terms < 2.5e-5 absolute — ignored.
    }
}

__global__ void finalize_kernel(const float* __restrict__ ws,
                                float* __restrict__ out) {
    out[(size_t)N_ROWS * ZD + N_ROWS] = ws[0] * (1.0f / 8388608.0f);
}

extern "C" void kernel_launch(void* const* d_in, const int* in_sizes, int n_in,
                              void* d_out, int out_size, void* d_ws, size_t ws_size,
                              hipStream_t stream) {
    const float* z = (const float*)d_in[0];
    const float* e = (const float*)d_in[1];
    float* out = (float*)d_out;
    float* ws  = (float*)d_ws;

    prep_kernel<<<dim3(8), dim3(256), 0, stream>>>(e, ws);
    vq_mfma<<<dim3(512), dim3(256), 0, stream>>>(z, e, ws, out);
    vq_fixup<<<dim3(1024), dim3(64), 0, stream>>>(z, e, ws, out);
    finalize_kernel<<<dim3(1), dim3(1), 0, stream>>>(ws, out);
}

// Round 6
// 256.197 us; speedup vs baseline: 4.0296x; 1.6056x over previous
//
#include <hip/hip_runtime.h>

// VQ quantizer, fp32: z [131072,64], e [2048,64].
// d_out (flat f32): z_q [131072*64] | indices [131072] (floats) | loss [1].
//
// 2-split bf16 MFMA scan (3 products: hh, hl, lh), argmax of s = dot - esq/2,
// acc initialized to -esq/2. Top-2 gap < EPS_S flags rows for exact f64
// re-solve (batched per block, coalesced via transposed e). T=0 => z_out =
// z_q = e[best]. __launch_bounds__(256,2): 2 waves/SIMD is the dispatch max
// anyway; 256-VGPR cap keeps A-fragments + argmin state register-resident
// (round-5's 88-VGPR allocation rematerialized A every iteration).

#define N_ROWS 131072
#define ZD 64
#define KCODES 2048
#define EPS_S 2e-3f          // gap on s-scale; d2-scale gap = 2x = 4e-3
#define BLK_CAP 64
#define SPILL_CAP 8192

using bf16x8  = __attribute__((ext_vector_type(8))) short;
using floatx4 = __attribute__((ext_vector_type(4))) float;

__device__ inline float bf2f(unsigned short u) {
    union { unsigned int i; float f; } c; c.i = ((unsigned int)u) << 16; return c.f;
}
__device__ inline unsigned short f2bf(float x) {
    union { float f; unsigned int i; } c; c.f = x;
    unsigned int b = c.i + 0x7FFFu + ((c.i >> 16) & 1u);
    return (unsigned short)(b >> 16);
}

// ws byte layout:
//       0: loss f32 | 4: spill count u32 | 16: counts u32[512]
//    4096: esn f32[2048] (= -esq/2, esq summed in f64)
//   16384: ehi u16[2048*64] | 278528: elo u16[2048*64]
//  540672: eT f32[64*2048]
// 1064960: blklist u32[512*64] | 1196032: spill u32[8192]

__global__ void prep_kernel(const float* __restrict__ e, float* __restrict__ ws) {
    int c = blockIdx.x * 256 + threadIdx.x;       // 8 blocks -> 2048 codes
    if (c == 0) { ws[0] = 0.0f; ((unsigned int*)ws)[1] = 0u; }
    unsigned int* counts = (unsigned int*)ws + 4;
    if (c < 512) counts[c] = 0u;
    float* esn = ws + 1024;
    unsigned short* ehi = (unsigned short*)((char*)ws + 16384);
    unsigned short* elo = (unsigned short*)((char*)ws + 278528);
    float* eT = (float*)((char*)ws + 540672);
    const float* p = e + (size_t)c * ZD;
    double s = 0.0;
    for (int k = 0; k < ZD; k++) {
        float x = p[k];
        s = fma((double)x, (double)x, s);
        unsigned short h = f2bf(x);
        ehi[c * ZD + k] = h;
        elo[c * ZD + k] = f2bf(x - bf2f(h));
        eT[k * KCODES + c] = x;                   // coalesced across threads
    }
    esn[c] = (float)(-0.5 * s);
}

__global__ __launch_bounds__(256, 2) void vq_mfma(
        const float* __restrict__ z, const float* __restrict__ e,
        float* __restrict__ ws, float* __restrict__ out) {
    const float* esn = ws + 1024;
    const unsigned short* ehi = (const unsigned short*)((const char*)ws + 16384);
    const unsigned short* elo = (const unsigned short*)((const char*)ws + 278528);
    unsigned int* counts  = (unsigned int*)ws + 4;
    unsigned int* blklist = (unsigned int*)((char*)ws + 1064960);
    unsigned int* spillc  = (unsigned int*)ws + 1;
    unsigned int* spill   = (unsigned int*)((char*)ws + 1196032);

    int lane = threadIdx.x & 63;
    int w    = threadIdx.x >> 6;
    int wid  = blockIdx.x * 4 + w;                // 0..2047
    int row0 = wid * 64;
    int lrow = lane & 15;
    int lq   = lane >> 4;

    // Resident A fragments (hi+lo), A[m=lane&15][k=lq*8+j]
    bf16x8 Ah[4][2], Al[4][2];
#pragma unroll
    for (int rf = 0; rf < 4; rf++)
#pragma unroll
        for (int kc = 0; kc < 2; kc++) {
            const float* zp = z + (size_t)(row0 + rf * 16 + lrow) * ZD + kc * 32 + lq * 8;
            float xv[8];
            *(float4*)(void*)&xv[0] = *(const float4*)(const void*)zp;
            *(float4*)(void*)&xv[4] = *(const float4*)(const void*)(zp + 4);
            bf16x8 h, l;
#pragma unroll
            for (int j = 0; j < 8; j++) {
                unsigned short hb = f2bf(xv[j]);
                h[j] = (short)hb;
                l[j] = (short)f2bf(xv[j] - bf2f(hb));
            }
            Ah[rf][kc] = h; Al[rf][kc] = l;
        }

    // argmax state on s = dot - esq/2  (argmin d2 == argmax s)
    floatx4 mval[4], mv2[4], midx[4];
#pragma unroll
    for (int rf = 0; rf < 4; rf++)
#pragma unroll
        for (int r = 0; r < 4; r++) {
            mval[rf][r] = -3.0e38f; mv2[rf][r] = -3.0e38f; midx[rf][r] = 0.0f;
        }

    const unsigned short* bh = ehi + lrow * ZD + lq * 8;
    const unsigned short* bl = elo + lrow * ZD + lq * 8;
    bf16x8 h0 = *(const bf16x8*)(const void*)(bh);
    bf16x8 h1 = *(const bf16x8*)(const void*)(bh + 32);
    bf16x8 l0 = *(const bf16x8*)(const void*)(bl);
    bf16x8 l1 = *(const bf16x8*)(const void*)(bl + 32);
    float  en = esn[lrow];

    for (int ct = 0; ct < 128; ct++) {
        int nn = ((ct + 1) & 127) * 16;           // next tile (wraps; harmless)
        int noff = nn * ZD;
        bf16x8 nh0 = *(const bf16x8*)(const void*)(bh + noff);
        bf16x8 nh1 = *(const bf16x8*)(const void*)(bh + noff + 32);
        bf16x8 nl0 = *(const bf16x8*)(const void*)(bl + noff);
        bf16x8 nl1 = *(const bf16x8*)(const void*)(bl + noff + 32);
        float  nen = esn[nn + lrow];

        float fcol = (float)(ct * 16 + lrow);
#pragma unroll
        for (int rf = 0; rf < 4; rf++) {
            floatx4 acc = {en, en, en, en};       // start at -esq/2
            acc = __builtin_amdgcn_mfma_f32_16x16x32_bf16(Ah[rf][0], h0, acc, 0, 0, 0);
            acc = __builtin_amdgcn_mfma_f32_16x16x32_bf16(Ah[rf][1], h1, acc, 0, 0, 0);
            acc = __builtin_amdgcn_mfma_f32_16x16x32_bf16(Ah[rf][0], l0, acc, 0, 0, 0);
            acc = __builtin_amdgcn_mfma_f32_16x16x32_bf16(Ah[rf][1], l1, acc, 0, 0, 0);
            acc = __builtin_amdgcn_mfma_f32_16x16x32_bf16(Al[rf][0], h0, acc, 0, 0, 0);
            acc = __builtin_amdgcn_mfma_f32_16x16x32_bf16(Al[rf][1], h1, acc, 0, 0, 0);
#pragma unroll
            for (int r = 0; r < 4; r++) {
                float s  = acc[r];
                bool  gt = s > mval[rf][r];
                mv2[rf][r]  = gt ? mval[rf][r] : fmaxf(mv2[rf][r], s);
                midx[rf][r] = gt ? fcol : midx[rf][r];
                mval[rf][r] = fmaxf(mval[rf][r], s);
            }
        }
        h0 = nh0; h1 = nh1; l0 = nl0; l1 = nl1; en = nen;
    }

    float lacc = 0.0f;
#pragma unroll
    for (int rf = 0; rf < 4; rf++)
#pragma unroll
        for (int r = 0; r < 4; r++) {
            float v = mval[rf][r], v2 = mv2[rf][r], fi = midx[rf][r];
            // top-2 max-merge across the 16 lanes of this row (ties: smaller col)
            for (int off = 1; off < 16; off <<= 1) {
                float ov  = __shfl_xor(v,  off, 64);
                float ofi = __shfl_xor(fi, off, 64);
                float ov2 = __shfl_xor(v2, off, 64);
                bool take = (ov > v) || ((ov == v) && (ofi < fi));
                float loser = take ? v : ov;
                v2 = fmaxf(fmaxf(v2, ov2), loser);
                v  = take ? ov  : v;
                fi = take ? ofi : fi;
            }
            int row = row0 + rf * 16 + lq * 4 + r;
            int idx = (int)fi;
            float4 ev = ((const float4*)(const void*)(e + (size_t)idx * ZD))[lrow];
            float4 zv = ((const float4*)(const void*)(z + (size_t)row * ZD))[lrow];
            ((float4*)(void*)(out + (size_t)row * ZD))[lrow] = ev;
            float dx = ev.x - zv.x, dy = ev.y - zv.y;
            float dz = ev.z - zv.z, dw = ev.w - zv.w;
            lacc = fmaf(dx, dx, lacc); lacc = fmaf(dy, dy, lacc);
            lacc = fmaf(dz, dz, lacc); lacc = fmaf(dw, dw, lacc);
            if (lrow == 0) {
                out[(size_t)N_ROWS * ZD + row] = fi;
                if (v - v2 < EPS_S) {
                    unsigned int i = atomicAdd(&counts[blockIdx.x], 1u);
                    if (i < BLK_CAP) blklist[blockIdx.x * BLK_CAP + i] = (unsigned int)row;
                    else {
                        unsigned int j = atomicAdd(spillc, 1u);
                        if (j < SPILL_CAP) spill[j] = (unsigned int)row;
                    }
                }
            }
        }

    for (int off = 1; off < 64; off <<= 1) lacc += __shfl_xor(lacc, off, 64);
    __shared__ float sm[4];
    if (lane == 0) sm[w] = lacc;
    __syncthreads();
    if (threadIdx.x == 0) atomicAdd(ws, sm[0] + sm[1] + sm[2] + sm[3]);
}

__device__ void fixup_row(int row, const float* __restrict__ z,
                          const float* __restrict__ e, const float* __restrict__ eT,
                          float* __restrict__ out,
                          double* sd, int* si, int* sbest) {
    int t = threadIdx.x, lane = t & 63, w = t >> 6;
    const float* zr = z + (size_t)row * ZD;
    double dacc[8];
#pragma unroll
    for (int j = 0; j < 8; j++) dacc[j] = 0.0;
    for (int k = 0; k < ZD; k++) {
        double zk = (double)zr[k];                // wave-uniform
#pragma unroll
        for (int j = 0; j < 8; j++) {
            double diff = zk - (double)eT[k * KCODES + t + 256 * j];
            dacc[j] = fma(diff, diff, dacc[j]);
        }
    }
    double dbest = 1.0e300; int ibest = 0;
#pragma unroll
    for (int j = 0; j < 8; j++) {                 // ascending c: first wins
        int c = t + 256 * j;
        if (dacc[j] < dbest) { dbest = dacc[j]; ibest = c; }
    }
    for (int off = 1; off < 64; off <<= 1) {
        double od = __shfl_xor(dbest, off, 64);
        int    oi = __shfl_xor(ibest, off, 64);
        if (od < dbest || (od == dbest && oi < ibest)) { dbest = od; ibest = oi; }
    }
    if (lane == 0) { sd[w] = dbest; si[w] = ibest; }
    __syncthreads();
    if (t == 0) {
        double bd = sd[0]; int bi = si[0];
        for (int q = 1; q < 4; q++)
            if (sd[q] < bd || (sd[q] == bd && si[q] < bi)) { bd = sd[q]; bi = si[q]; }
        *sbest = bi;
    }
    __syncthreads();
    int bi = *sbest;
    if (t < 16)
        ((float4*)(void*)(out + (size_t)row * ZD))[t] =
            ((const float4*)(const void*)(e + (size_t)bi * ZD))[t];
    if (t == 0) out[(size_t)N_ROWS * ZD + row] = (float)bi;
    __syncthreads();
    // loss correction from flips: < EPS * flagged / 8.4M < 1e-9 — ignored.
}

__global__ __launch_bounds__(256) void vq_fixup(
        const float* __restrict__ z, const float* __restrict__ e,
        float* __restrict__ ws, float* __restrict__ out) {
    const float* eT = (const float*)((const char*)ws + 540672);
    const unsigned int* counts  = (const unsigned int*)ws + 4;
    const unsigned int* blklist = (const unsigned int*)((const char*)ws + 1064960);
    const unsigned int* spill   = (const unsigned int*)((const char*)ws + 1196032);
    __shared__ double sd[4]; __shared__ int si[4]; __shared__ int sbest;

    unsigned int cnt = counts[blockIdx.x];
    if (cnt > BLK_CAP) cnt = BLK_CAP;
    for (unsigned int i = 0; i < cnt; i++)
        fixup_row((int)blklist[blockIdx.x * BLK_CAP + i], z, e, eT, out, sd, si, &sbest);

    unsigned int sp = ((const unsigned int*)ws)[1];
    if (sp > SPILL_CAP) sp = SPILL_CAP;
    for (unsigned int u = blockIdx.x; u < sp; u += 512)
        fixup_row((int)spill[u], z, e, eT, out, sd, si, &sbest);
}

__global__ void finalize_kernel(const float* __restrict__ ws,
                                float* __restrict__ out) {
    out[(size_t)N_ROWS * ZD + N_ROWS] = ws[0] * (1.0f / 8388608.0f);
}

extern "C" void kernel_launch(void* const* d_in, const int* in_sizes, int n_in,
                              void* d_out, int out_size, void* d_ws, size_t ws_size,
                              hipStream_t stream) {
    const float* z = (const float*)d_in[0];
    const float* e = (const float*)d_in[1];
    float* out = (float*)d_out;
    float* ws  = (float*)d_ws;

    prep_kernel<<<dim3(8), dim3(256), 0, stream>>>(e, ws);
    vq_mfma<<<dim3(512), dim3(256), 0, stream>>>(z, e, ws, out);
    vq_fixup<<<dim3(512), dim3(256), 0, stream>>>(z, e, ws, out);
    finalize_kernel<<<dim3(1), dim3(1), 0, stream>>>(ws, out);
}